// Round 7
// baseline (190.659 us; speedup 1.0000x reference)
//
#include <hip/hip_runtime.h>

// Sin/cos position embedding. 128 MiB written, 64 KiB read -> write-BW bound.
//
// R4-R7 = INSTRUMENTATION ROUND (will revert): the kernel has never appeared
// in the rocprof top-5 (all slots taken by 82-88us harness fills), so its
// true duration/BW is unknown -- bench dur (133.8us) is ambiguous between
// "kernel=48us, capped at 2.7 TB/s" and "kernel=23us at roofline + ~110us
// harness overhead". This version sweeps the output 4x inside ONE dispatch
// (idempotent; asm memory barrier between sweeps blocks DSE; 16 MiB/XCD
// per-sweep footprint >> 4 MiB L2 so every sweep reaches DRAM). Two
// independent discriminating channels:
//   (1) bench dur: OH + 4K = ~278us if K=48, ~203us if K=23;
//   (2) rocprof: the ~4K>=92us dispatch enters top-5 with its own
//       hbm_gbps / WRITE_SIZE / VALUBusy / Occupancy.
// (R4/R5/R6 benches all failed at broker ACQUIRE -- source never ran;
// acquire happens before source push, so failures are content-independent.
// Resubmitting identical source.)
//
// Decision rule: hbm_gbps >= ~5500 -> revert & declare roofline;
//                ~2700 -> cap is real, attack per its counters.

#define RPW 8          // rows per wave (64 KiB span / 8 KiB row)
#define NW  8          // column windows: q/64 = 512/64
#define SWEEPS 4       // instrumentation: rewrite output 4x (idempotent)

__global__ __launch_bounds__(256) void sinpos_kernel(
    const float* __restrict__ t,
    float4* __restrict__ out,
    int q,                // D/4 = float4s per row (== 512)
    float c)              // -2*log2(N_BASE)/D, so inv_freq = exp2(c*i)
{
    int lane = threadIdx.x & 63;
    int wid  = blockIdx.x * 4 + (threadIdx.x >> 6);   // global wave id
    int b0   = wid * RPW;                             // first row of span

    // 8 frequency pairs: window w covers float4 columns [w*64, w*64+64).
    float f0[NW], f1[NW];
#pragma unroll
    for (int w = 0; w < NW; ++w) {
        float i0 = (float)(2 * (w * 64 + lane));
        f0[w] = __builtin_amdgcn_exp2f(c * i0);
        f1[w] = __builtin_amdgcn_exp2f(c * (i0 + 1.0f));
    }

    // Prefetch the span's t values (fold 1/2pi for the fract-based sincos).
    const float inv2pi = 0.15915494309189535f;
    float ts[RPW];
#pragma unroll
    for (int r = 0; r < RPW; ++r) ts[r] = t[b0 + r] * inv2pi;

    // Linear sweep: 64 consecutive 1-KiB wave-stores, 64 KiB per wave.
    float4* p = out + (size_t)b0 * q + lane;
    for (int s = 0; s < SWEEPS; ++s) {
#pragma unroll
        for (int r = 0; r < RPW; ++r) {
#pragma unroll
            for (int w = 0; w < NW; ++w) {
                float r0 = ts[r] * f0[w]; r0 -= __builtin_floorf(r0);
                float r1 = ts[r] * f1[w]; r1 -= __builtin_floorf(r1);
                float4 v;
                v.x = __builtin_amdgcn_sinf(r0);
                v.y = __builtin_amdgcn_cosf(r0);
                v.z = __builtin_amdgcn_sinf(r1);
                v.w = __builtin_amdgcn_cosf(r1);
                p[(r * NW + w) * 64] = v;
            }
        }
        asm volatile("" ::: "memory");   // block dead-store elim across sweeps
    }
}

extern "C" void kernel_launch(void* const* d_in, const int* in_sizes, int n_in,
                              void* d_out, int out_size, void* d_ws, size_t ws_size,
                              hipStream_t stream) {
    const float* t = (const float*)d_in[0];
    float* out = (float*)d_out;

    int B = in_sizes[0];             // 16384
    int D = out_size / B;            // 2048
    int q = D / 4;                   // 512 float4s per row

    // c = -2*log2(10000)/D ; log2(10000) = 13.287712379549449
    float c = (float)(-2.0 * 13.287712379549449 / (double)D);

    dim3 block(256);
    dim3 grid(B / (RPW * 4));        // one 64-KiB span per wave: 512 blocks
    sinpos_kernel<<<grid, block, 0, stream>>>(t, (float4*)out, q, c);
}

// Round 8
// 133.845 us; speedup vs baseline: 1.4245x; 1.4245x over previous
//
#include <hip/hip_runtime.h>

// Sin/cos position embedding: out[b, 2i] = sin(t[b] * N^(-2i/D)),
//                             out[b, 2i+1] = cos(t[b] * N^(-2i/D))
// 128 MiB written, 64 KiB read -> pure write-BW problem.
//
// ROOFLINE EVIDENCE (R7 instrumented 4-sweep run): this kernel's store loop
// measured 6435-6472 GB/s (80.4-80.9% of 8 TB/s spec) -- identical to the
// harness fillBufferAligned ceiling on the same chip (6410-6468). VALUBusy
// 5%, FETCH 91 KB, 0 bank conflicts. Single sweep = 128 MiB / 6.45 TB/s
// ~= 21 us; the rest of the benched 134 us is harness re-poison overhead
// (OH ~= 115 us, solved from OH+K=133.8 / OH+4K=190.7). Store path is AT
// the achievable write roofline; NT stores (R2) and stream restructuring
// (R3) were neutral because there was no store-path headroom to recover.
//
// Structure: each WAVE owns one contiguous 64-KiB span (8 rows) and sweeps
// it linearly -- 64 back-to-back 1-KiB wave-stores at consecutive
// addresses. 512 blocks x 256 thr = 8 waves/CU (BW saturates at ~3).
// Per thread: 8 column-windows -> 8 (f0,f1) freq pairs precomputed
// (16 exp2 prologue) + 8 t-values, then a fully-unrolled 8x8 store loop
// with zero memory dependencies in the body.
//
// Shape assumptions (bench-fixed): D == 2048 (q == 512, 8 windows of 64),
// B % 32 == 0.

#define RPW 8          // rows per wave (64 KiB span / 8 KiB row)
#define NW  8          // column windows: q/64 = 512/64

__global__ __launch_bounds__(256) void sinpos_kernel(
    const float* __restrict__ t,
    float4* __restrict__ out,
    int q,                // D/4 = float4s per row (== 512)
    float c)              // -2*log2(N_BASE)/D, so inv_freq = exp2(c*i)
{
    int lane = threadIdx.x & 63;
    int wid  = blockIdx.x * 4 + (threadIdx.x >> 6);   // global wave id
    int b0   = wid * RPW;                             // first row of span

    // 8 frequency pairs: window w covers float4 columns [w*64, w*64+64).
    float f0[NW], f1[NW];
#pragma unroll
    for (int w = 0; w < NW; ++w) {
        float i0 = (float)(2 * (w * 64 + lane));
        f0[w] = __builtin_amdgcn_exp2f(c * i0);
        f1[w] = __builtin_amdgcn_exp2f(c * (i0 + 1.0f));
    }

    // Prefetch the span's t values (fold 1/2pi for the fract-based sincos).
    const float inv2pi = 0.15915494309189535f;
    float ts[RPW];
#pragma unroll
    for (int r = 0; r < RPW; ++r) ts[r] = t[b0 + r] * inv2pi;

    // Linear sweep: store g = b0*q + (r*NW + w)*64 + lane -- consecutive
    // 1-KiB wave-stores at consecutive addresses, 64 KiB total per wave.
    float4* p = out + (size_t)b0 * q + lane;
#pragma unroll
    for (int r = 0; r < RPW; ++r) {
#pragma unroll
        for (int w = 0; w < NW; ++w) {
            float r0 = ts[r] * f0[w]; r0 -= __builtin_floorf(r0);
            float r1 = ts[r] * f1[w]; r1 -= __builtin_floorf(r1);
            float4 v;
            v.x = __builtin_amdgcn_sinf(r0);
            v.y = __builtin_amdgcn_cosf(r0);
            v.z = __builtin_amdgcn_sinf(r1);
            v.w = __builtin_amdgcn_cosf(r1);
            p[(r * NW + w) * 64] = v;
        }
    }
}

extern "C" void kernel_launch(void* const* d_in, const int* in_sizes, int n_in,
                              void* d_out, int out_size, void* d_ws, size_t ws_size,
                              hipStream_t stream) {
    const float* t = (const float*)d_in[0];
    float* out = (float*)d_out;

    int B = in_sizes[0];             // 16384
    int D = out_size / B;            // 2048
    int q = D / 4;                   // 512 float4s per row

    // c = -2*log2(10000)/D ; log2(10000) = 13.287712379549449
    float c = (float)(-2.0 * 13.287712379549449 / (double)D);

    dim3 block(256);
    dim3 grid(B / (RPW * 4));        // one 64-KiB span per wave: 512 blocks
    sinpos_kernel<<<grid, block, 0, stream>>>(t, (float4*)out, q, c);
}